// Round 1
// 647.200 us; speedup vs baseline: 1.0034x; 1.0034x over previous
//
#include <hip/hip_runtime.h>
#include <math.h>

// Problem constants
constexpr int B  = 8;
constexpr int C  = 256;   // Cin
constexpr int M  = 256;
constexpr int O  = 256;
constexpr int H  = 128;
constexpr int W  = 128;
constexpr int HW = H * W; // 16384
constexpr int K  = 128;   // top-k / kept channels

using f16  = _Float16;
using f16x8 = __attribute__((ext_vector_type(8))) _Float16;
using f32x4 = __attribute__((ext_vector_type(4))) float;

// Workspace layout (offsets in float units)
constexpr size_t WS_MEANX = 0;        // 2048
constexpr size_t WS_MASK  = 2048;     // 2048
constexpr size_t WS_G2    = 4096;     // 2048
constexpr size_t WS_OFF   = 6144;     // 48 (pad to 64)
constexpr size_t WS_WE3   = 6208;     // 9216
constexpr size_t WS_WE5   = 15424;    // 25600
constexpr size_t WS_WE7   = 41024;    // 50176
constexpr size_t WS_WT1F  = 91200;    // 65536 f16 -> 32768 slots  (pw1_w as f16, [o][c])
constexpr size_t WS_WT2F  = 123968;   // 98304 f16 -> 49152 slots  (pw_w[:, :384] as f16, [o][cc])
constexpr size_t WS_SELH  = 173120;   // B*K*HW f16 -> 8388608 slots (33.5 MB)
constexpr size_t WS_YH    = 8561728;  // 3*B*K*HW f16 -> 25165824 slots (100.6 MB)
// end = 33727552 floats = 134.91 MB (<= previous proven 135.27 MB footprint)

// ---------------------------------------------------------------------------
// Kernel A: meanx[b][c] = mean over HW of x; also zero gap2sum accumulator.
// ---------------------------------------------------------------------------
__global__ __launch_bounds__(256) void kA(const float* __restrict__ x,
                                          float* __restrict__ ws) {
  float* meanx   = ws + WS_MEANX;
  float* gap2sum = ws + WS_G2;
  int plane = blockIdx.x;  // b*C + c
  const float* p = x + (size_t)plane * HW;
  float s = 0.f;
  for (int i = threadIdx.x; i < HW / 4; i += 256) {
    float4 v = ((const float4*)p)[i];
    s += v.x + v.y + v.z + v.w;
  }
  __shared__ float red[256];
  red[threadIdx.x] = s;
  __syncthreads();
  for (int off = 128; off > 0; off >>= 1) {
    if (threadIdx.x < off) red[threadIdx.x] += red[threadIdx.x + off];
    __syncthreads();
  }
  if (threadIdx.x == 0) meanx[plane] = red[0] * (1.f / HW);
  if (blockIdx.x < 8) gap2sum[blockIdx.x * 256 + threadIdx.x] = 0.f;
}

// ---------------------------------------------------------------------------
// Kernel T: f16 copies of pw1_w ([o][c], K-contiguous) and pw_w[:, :384].
// ---------------------------------------------------------------------------
__global__ __launch_bounds__(256) void kT(const float* __restrict__ pw1_w,
                                          const float* __restrict__ pw_w,
                                          float* __restrict__ ws) {
  f16* wt1f = (f16*)(ws + WS_WT1F);
  f16* wt2f = (f16*)(ws + WS_WT2F);
  int t = blockIdx.x * 256 + threadIdx.x;
  if (t < C * M) wt1f[t] = (f16)pw1_w[t];
  if (t < 384 * O) {
    int o = t / 384, cc = t % 384;
    wt2f[t] = (f16)pw_w[(size_t)o * 768 + cc];
  }
}

// ---------------------------------------------------------------------------
// Kernel B: per-batch block; exact fp32 scoring path (unchanged from R2).
// ---------------------------------------------------------------------------
__global__ __launch_bounds__(256) void kB(const float* __restrict__ pw1_w,
                                          const float* __restrict__ pw1_b,
                                          const float* __restrict__ fc1_w,
                                          const float* __restrict__ fc1_b,
                                          const float* __restrict__ fc2_w,
                                          const float* __restrict__ fc2_b,
                                          float* __restrict__ ws) {
  int b = blockIdx.x;
  const float* meanx = ws + WS_MEANX + b * C;
  float* maskg = ws + WS_MASK;
  __shared__ float s_gap[M];
  __shared__ float s_hid[512];
  __shared__ float s_sc[M];
  int t = threadIdx.x;
  int lane = t & 63, wv = t >> 6;

  float4 mx = ((const float4*)meanx)[lane];
  for (int o0 = wv * 64; o0 < wv * 64 + 64; o0 += 4) {
    float s[4];
#pragma unroll
    for (int j = 0; j < 4; j++) {
      float4 w = ((const float4*)(pw1_w + (size_t)(o0 + j) * C))[lane];
      s[j] = mx.x * w.x + mx.y * w.y + mx.z * w.z + mx.w * w.w;
    }
#pragma unroll
    for (int off = 32; off > 0; off >>= 1)
#pragma unroll
      for (int j = 0; j < 4; j++) s[j] += __shfl_xor(s[j], off, 64);
    if (lane == 0) {
#pragma unroll
      for (int j = 0; j < 4; j++) s_gap[o0 + j] = s[j] + pw1_b[o0 + j];
    }
  }
  __syncthreads();

  float4 g4 = ((const float4*)s_gap)[lane];
  for (int j0 = wv * 128; j0 < wv * 128 + 128; j0 += 4) {
    float s[4];
#pragma unroll
    for (int j = 0; j < 4; j++) {
      float4 w = ((const float4*)(fc1_w + (size_t)(j0 + j) * M))[lane];
      s[j] = g4.x * w.x + g4.y * w.y + g4.z * w.z + g4.w * w.w;
    }
#pragma unroll
    for (int off = 32; off > 0; off >>= 1)
#pragma unroll
      for (int j = 0; j < 4; j++) s[j] += __shfl_xor(s[j], off, 64);
    if (lane == 0) {
#pragma unroll
      for (int j = 0; j < 4; j++) {
        float v = s[j] + fc1_b[j0 + j];
        s_hid[j0 + j] = v > 0.f ? v : 0.f;
      }
    }
  }
  __syncthreads();

  float4 h0 = ((const float4*)s_hid)[lane];
  float4 h1 = ((const float4*)s_hid)[lane + 64];
  for (int o0 = wv * 64; o0 < wv * 64 + 64; o0 += 4) {
    float s[4];
#pragma unroll
    for (int j = 0; j < 4; j++) {
      const float4* wr = (const float4*)(fc2_w + (size_t)(o0 + j) * 512);
      float4 w0 = wr[lane];
      float4 w1 = wr[lane + 64];
      s[j] = h0.x * w0.x + h0.y * w0.y + h0.z * w0.z + h0.w * w0.w +
             h1.x * w1.x + h1.y * w1.y + h1.z * w1.z + h1.w * w1.w;
    }
#pragma unroll
    for (int off = 32; off > 0; off >>= 1)
#pragma unroll
      for (int j = 0; j < 4; j++) s[j] += __shfl_xor(s[j], off, 64);
    if (lane == 0) {
#pragma unroll
      for (int j = 0; j < 4; j++) {
        float v = s[j] + fc2_b[o0 + j];
        s_sc[o0 + j] = 1.f / (1.f + expf(-v));
      }
    }
  }
  __syncthreads();

  {
    int j = t;
    float sj = s_sc[j];
    int cnt = 0;
    for (int m = 0; m < M; m++) {
      float sm = s_sc[m];
      cnt += (sm > sj) || (sm == sj && m < j);
    }
    maskg[b * M + j] = (cnt < K) ? 1.f : 0.f;
  }
}

// ---------------------------------------------------------------------------
// Kernel Cm: h = relu(pw1(x)) via f16 MFMA. Block = 256 o x 64 p, K=256.
// B-stage: coalesced float4 loads along pixels + swizzled ds_write_b128
// (LDS transpose); frag reads are conflict-free u16 gathers.
// Next-step global loads prefetched into registers (hide latency under MFMA).
// ---------------------------------------------------------------------------
__global__ __launch_bounds__(256) void kCm(const float* __restrict__ x,
                                           const float* __restrict__ pw1_b,
                                           float* __restrict__ ws) {
  const f16* wt1f = (const f16*)(ws + WS_WT1F);
  float* gap2sum  = ws + WS_G2;
  f16* selh       = (f16*)(ws + WS_SELH);
  int b  = blockIdx.z;
  int p0 = blockIdx.x * 64;
  __shared__ f16 Af[256 * 32];  // 1024 chunks of 16B, fragment-linear
  __shared__ f16 Bf[64 * 32];   // 32 c-rows x 64 px, chunk-swizzled

  int t = threadIdx.x, l = t & 63, w = t >> 6;
  int q = l >> 4, n = l & 15;
  const float* xb = x + (size_t)b * C * HW;

  // B-stage indices: thread t handles (c-row = t>>3, pixel-octet = t&7)
  int crow = t >> 3;                 // 0..31
  int oct  = t & 7;                  // 0..7
  int qc_s = (crow >> 3) & 3;
  int posB = crow * 64 + (((oct >> 1) ^ qc_s) << 4) + (oct & 1) * 8;  // f16 units

  // A-stage source offsets (same fragment-linear chunk mapping as before)
  int aoff[4];
#pragma unroll
  for (int i = 0; i < 4; i++) {
    int ch = t + i * 256;
    aoff[i] = ((ch >> 6) * 16 + (ch & 15)) * C + ((ch >> 4) & 3) * 8;
  }

  f32x4 acc[4][4];
#pragma unroll
  for (int i = 0; i < 4; i++)
#pragma unroll
    for (int j = 0; j < 4; j++)
#pragma unroll
      for (int r = 0; r < 4; r++) acc[i][j][r] = 0.f;

  f16x8 rA[4];
  float4 rB0, rB1;
  auto loadA = [&](int k0) {
#pragma unroll
    for (int i = 0; i < 4; i++) rA[i] = *(const f16x8*)&wt1f[aoff[i] + k0];
  };
  auto loadB = [&](int k0) {
    const float* bs = xb + (size_t)(k0 + crow) * HW + p0 + oct * 8;
    rB0 = ((const float4*)bs)[0];
    rB1 = ((const float4*)bs)[1];
  };
  loadA(0);
  loadB(0);

  for (int k0 = 0; k0 < C; k0 += 32) {
    __syncthreads();  // prev-step frag reads done; LDS reusable
#pragma unroll
    for (int i = 0; i < 4; i++) ((f16x8*)Af)[t + i * 256] = rA[i];
    {
      f16x8 bv;
      bv[0] = (f16)rB0.x; bv[1] = (f16)rB0.y; bv[2] = (f16)rB0.z; bv[3] = (f16)rB0.w;
      bv[4] = (f16)rB1.x; bv[5] = (f16)rB1.y; bv[6] = (f16)rB1.z; bv[7] = (f16)rB1.w;
      *(f16x8*)&Bf[posB] = bv;
    }
    if (k0 + 32 < C) { loadA(k0 + 32); loadB(k0 + 32); }  // prefetch next step
    __syncthreads();
    f16x8 bfr[4], afr[4];
#pragma unroll
    for (int nt = 0; nt < 4; nt++) {
      f16x8 fr;
#pragma unroll
      for (int j = 0; j < 8; j++)
        fr[j] = Bf[(q * 8 + j) * 64 + ((nt ^ q) << 4) + n];
      bfr[nt] = fr;
    }
#pragma unroll
    for (int mt = 0; mt < 4; mt++) afr[mt] = ((const f16x8*)Af)[(w * 4 + mt) * 64 + l];
#pragma unroll
    for (int mt = 0; mt < 4; mt++)
#pragma unroll
      for (int nt = 0; nt < 4; nt++)
        acc[mt][nt] = __builtin_amdgcn_mfma_f32_16x16x32_f16(afr[mt], bfr[nt],
                                                             acc[mt][nt], 0, 0, 0);
  }

  // Epilogue: bias + relu; sel f16 store (o<128); gap2sum partial sums
#pragma unroll
  for (int mt = 0; mt < 4; mt++) {
    float rsum[4] = {0.f, 0.f, 0.f, 0.f};
    int obase = w * 64 + mt * 16 + q * 4;
    float bias[4];
#pragma unroll
    for (int r = 0; r < 4; r++) bias[r] = pw1_b[obase + r];
#pragma unroll
    for (int nt = 0; nt < 4; nt++) {
      int p = p0 + nt * 16 + n;
#pragma unroll
      for (int r = 0; r < 4; r++) {
        float h = acc[mt][nt][r] + bias[r];
        h = h > 0.f ? h : 0.f;
        rsum[r] += h;
        int o = obase + r;
        if (o < K) selh[((size_t)(b * K + o)) * HW + p] = (f16)h;
      }
    }
#pragma unroll
    for (int off = 1; off < 16; off <<= 1)
#pragma unroll
      for (int r = 0; r < 4; r++) rsum[r] += __shfl_xor(rsum[r], off, 64);
    if (n == 0) {
#pragma unroll
      for (int r = 0; r < 4; r++)
        atomicAdd(&gap2sum[b * M + obase + r], rsum[r]);
    }
  }
}

// ---------------------------------------------------------------------------
// Kernel D1 (1 block): offsets from gap2; emit per-(b,branch) scale/shift.
// ---------------------------------------------------------------------------
__global__ __launch_bounds__(256) void kD1(const float* __restrict__ off_w,
                                           const float* __restrict__ off_b,
                                           float* __restrict__ ws) {
  const float* gap2sum = ws + WS_G2;
  float* offv = ws + WS_OFF;  // [0..23]=scale(b*3+i), [24..47]=shift
  __shared__ float s_off[48];
  int t = threadIdx.x;
  int lane = t & 63, wv = t >> 6;
  for (int id = wv; id < 48; id += 4) {
    int b = id / 6, j = id % 6;
    float4 g = ((const float4*)(gap2sum + b * M))[lane];
    float4 w = ((const float4*)(off_w + (size_t)j * M))[lane];
    float s = (g.x * w.x + g.y * w.y + g.z * w.z + g.w * w.w) * (1.f / HW);
#pragma unroll
    for (int off = 32; off > 0; off >>= 1) s += __shfl_xor(s, off, 64);
    if (lane == 0) s_off[id] = tanhf(s + off_b[j]);
  }
  __syncthreads();
  if (t < 24) {
    int b = t / 3, i = t % 3;
    offv[t]      = 1.f + 1.f / (1.f + expf(-s_off[b * 6 + 2 * i]));
    offv[24 + t] = tanhf(s_off[b * 6 + 2 * i + 1]);
  }
}

// ---------------------------------------------------------------------------
// Kernel D2: effective depthwise weights, with top-k mask folded in.
// ---------------------------------------------------------------------------
__global__ __launch_bounds__(256) void kD2(const float* __restrict__ dw3,
                                           const float* __restrict__ dw5,
                                           const float* __restrict__ dw7,
                                           float* __restrict__ ws) {
  const float* offv  = ws + WS_OFF;
  const float* maskg = ws + WS_MASK;
  float* wE3 = ws + WS_WE3;
  float* wE5 = ws + WS_WE5;
  float* wE7 = ws + WS_WE7;
  int tid = blockIdx.x * 256 + threadIdx.x;
  int stride = gridDim.x * 256;
  for (int i = tid; i < B * K * 9; i += stride) {
    int b = i / (K * 9), rem = i % (K * 9), c = rem / 9;
    wE3[i] = (dw3[rem] * offv[b * 3 + 0] + offv[24 + b * 3 + 0]) * maskg[b * M + c];
  }
  for (int i = tid; i < B * K * 25; i += stride) {
    int b = i / (K * 25), rem = i % (K * 25), c = rem / 25;
    wE5[i] = (dw5[rem] * offv[b * 3 + 1] + offv[24 + b * 3 + 1]) * maskg[b * M + c];
  }
  for (int i = tid; i < B * K * 49; i += stride) {
    int b = i / (K * 49), rem = i % (K * 49), c = rem / 49;
    wE7[i] = (dw7[rem] * offv[b * 3 + 2] + offv[24 + b * 3 + 2]) * maskg[b * M + c];
  }
}

// ---------------------------------------------------------------------------
// Kernel Em: merged depthwise conv — one halo fill (P=3 superset), all three
// kernel sizes computed per plane chunk; f16 in, f16 out x3 branches.
// ---------------------------------------------------------------------------
__global__ __launch_bounds__(256) void kEm(const float* __restrict__ ws_ro,
                                           float* __restrict__ ws) {
  constexpr int SH = 38, SW = 134;  // 32+2*3, 128+2*3
  __shared__ float sm[SH][SW];
  const f16* selh = (const f16*)(ws_ro + WS_SELH);
  f16* yh         = (f16*)(ws + WS_YH);
  int blk = blockIdx.x;
  int chunk = blk & 3;
  int plane = blk >> 2;  // b*K + c
  int b = plane >> 7, c = plane & 127;
  int r0 = chunk * 32;
  const f16* in = selh + (size_t)plane * HW;
  for (int i = threadIdx.x; i < SH * SW; i += 256) {
    int rr = i / SW, cc = i % SW;
    int gy = r0 - 3 + rr, gx = cc - 3;
    float v = 0.f;
    if (gy >= 0 && gy < H && gx >= 0 && gx < W) v = (float)in[gy * W + gx];
    sm[rr][cc] = v;
  }
  __syncthreads();
  int col   = threadIdx.x & 127;
  int rhalf = threadIdx.x >> 7;

  const float* wE[3] = {ws_ro + WS_WE3 + (size_t)plane * 9,
                        ws_ro + WS_WE5 + (size_t)plane * 25,
                        ws_ro + WS_WE7 + (size_t)plane * 49};

#define CONV_BRANCH(KS, BR)                                                    \
  {                                                                            \
    constexpr int P = (KS - 1) / 2;                                            \
    float w[KS * KS];                                                          \
    _Pragma("unroll") for (int i = 0; i < KS * KS; i++) w[i] = wE[BR][i];      \
    float acc[16];                                                             \
    _Pragma("unroll") for (int r = 0; r < 16; r++) acc[r] = 0.f;               \
    _Pragma("unroll") for (int iy = 0; iy < 16 + 2 * P; iy++) {                \
      float v[KS];                                                             \
      _Pragma("unroll") for (int dx = 0; dx < KS; dx++)                        \
          v[dx] = sm[rhalf * 16 + iy + (3 - P)][col + (3 - P) + dx];           \
      _Pragma("unroll") for (int rr = 0; rr < 16; rr++) {                      \
        int dy = iy - rr;                                                      \
        if (dy >= 0 && dy < KS) {                                              \
          _Pragma("unroll") for (int dx = 0; dx < KS; dx++)                    \
              acc[rr] += v[dx] * w[dy * KS + dx];                              \
        }                                                                      \
      }                                                                        \
    }                                                                          \
    f16* outp = yh + ((size_t)(BR * B + b) * K + c) * HW;                      \
    _Pragma("unroll") for (int rr = 0; rr < 16; rr++)                          \
        outp[(size_t)(r0 + rhalf * 16 + rr) * W + col] = (f16)acc[rr];         \
  }

  CONV_BRANCH(3, 0)
  CONV_BRANCH(5, 1)
  CONV_BRANCH(7, 2)
#undef CONV_BRANCH
}

// ---------------------------------------------------------------------------
// Kernel Fm: merged final pointwise, f16 MFMA, K=384 (all 3 branches).
// Block = 256 o x 64 p. B-stage: coalesced f16x8 loads along pixels +
// swizzled ds_write_b128 (LDS transpose); conflict-free u16 frag reads.
// Next-step global loads prefetched into registers.
// ---------------------------------------------------------------------------
__global__ __launch_bounds__(256) void kFm(const float* __restrict__ x,
                                           const float* __restrict__ pw_b,
                                           const float* __restrict__ ws,
                                           float* __restrict__ out) {
  const f16* wt2f = (const f16*)(ws + WS_WT2F);
  const f16* yh   = (const f16*)(ws + WS_YH);
  int b  = blockIdx.z;
  int p0 = blockIdx.x * 64;
  __shared__ f16 Af[256 * 32];
  __shared__ f16 Bf[64 * 32];

  int t = threadIdx.x, l = t & 63, w = t >> 6;
  int q = l >> 4, n = l & 15;

  int crow = t >> 3;                 // 0..31
  int oct  = t & 7;                  // 0..7
  int qc_s = (crow >> 3) & 3;
  int posB = crow * 64 + (((oct >> 1) ^ qc_s) << 4) + (oct & 1) * 8;  // f16 units

  int aoff[4];
#pragma unroll
  for (int i = 0; i < 4; i++) {
    int ch = t + i * 256;
    aoff[i] = ((ch >> 6) * 16 + (ch & 15)) * 384 + ((ch >> 4) & 3) * 8;
  }

  f32x4 acc[4][4];
#pragma unroll
  for (int i = 0; i < 4; i++)
#pragma unroll
    for (int j = 0; j < 4; j++)
#pragma unroll
      for (int r = 0; r < 4; r++) acc[i][j][r] = 0.f;

  f16x8 rA[4], rB;
  auto loadA = [&](int k0) {
#pragma unroll
    for (int i = 0; i < 4; i++) rA[i] = *(const f16x8*)&wt2f[aoff[i] + k0];
  };
  auto loadB = [&](int k0) {
    int br = k0 >> 7, kk = k0 & 127;
    const f16* ybr = yh + (size_t)(br * B + b) * K * HW;
    rB = *(const f16x8*)&ybr[(size_t)(kk + crow) * HW + p0 + oct * 8];
  };
  loadA(0);
  loadB(0);

  for (int k0 = 0; k0 < 384; k0 += 32) {
    __syncthreads();
#pragma unroll
    for (int i = 0; i < 4; i++) ((f16x8*)Af)[t + i * 256] = rA[i];
    *(f16x8*)&Bf[posB] = rB;
    if (k0 + 32 < 384) { loadA(k0 + 32); loadB(k0 + 32); }  // prefetch
    __syncthreads();
    f16x8 bfr[4], afr[4];
#pragma unroll
    for (int nt = 0; nt < 4; nt++) {
      f16x8 fr;
#pragma unroll
      for (int j = 0; j < 8; j++)
        fr[j] = Bf[(q * 8 + j) * 64 + ((nt ^ q) << 4) + n];
      bfr[nt] = fr;
    }
#pragma unroll
    for (int mt = 0; mt < 4; mt++) afr[mt] = ((const f16x8*)Af)[(w * 4 + mt) * 64 + l];
#pragma unroll
    for (int mt = 0; mt < 4; mt++)
#pragma unroll
      for (int nt = 0; nt < 4; nt++)
        acc[mt][nt] = __builtin_amdgcn_mfma_f32_16x16x32_f16(afr[mt], bfr[nt],
                                                             acc[mt][nt], 0, 0, 0);
  }

#pragma unroll
  for (int mt = 0; mt < 4; mt++) {
    int obase = w * 64 + mt * 16 + q * 4;
    float bias[4];
#pragma unroll
    for (int r = 0; r < 4; r++) bias[r] = pw_b[obase + r];
#pragma unroll
    for (int nt = 0; nt < 4; nt++) {
      int p = p0 + nt * 16 + n;
#pragma unroll
      for (int r = 0; r < 4; r++) {
        size_t idx = ((size_t)b * O + obase + r) * HW + p;
        out[idx] = acc[mt][nt][r] + bias[r] + x[idx];
      }
    }
  }
}

// ---------------------------------------------------------------------------
extern "C" void kernel_launch(void* const* d_in, const int* in_sizes, int n_in,
                              void* d_out, int out_size, void* d_ws, size_t ws_size,
                              hipStream_t stream) {
  const float* x     = (const float*)d_in[0];
  const float* pw1_w = (const float*)d_in[1];
  const float* pw1_b = (const float*)d_in[2];
  const float* fc1_w = (const float*)d_in[3];
  const float* fc1_b = (const float*)d_in[4];
  const float* fc2_w = (const float*)d_in[5];
  const float* fc2_b = (const float*)d_in[6];
  const float* off_w = (const float*)d_in[7];
  const float* off_b = (const float*)d_in[8];
  const float* dw3   = (const float*)d_in[9];
  const float* dw5   = (const float*)d_in[10];
  const float* dw7   = (const float*)d_in[11];
  const float* pw_w  = (const float*)d_in[12];
  const float* pw_b  = (const float*)d_in[13];
  float* out = (float*)d_out;
  float* ws  = (float*)d_ws;

  kA<<<B * C, 256, 0, stream>>>(x, ws);
  kT<<<384, 256, 0, stream>>>(pw1_w, pw_w, ws);
  kB<<<B, 256, 0, stream>>>(pw1_w, pw1_b, fc1_w, fc1_b, fc2_w, fc2_b, ws);
  kCm<<<dim3(HW / 64, 1, B), 256, 0, stream>>>(x, pw1_b, ws);
  kD1<<<1, 256, 0, stream>>>(off_w, off_b, ws);
  kD2<<<84, 256, 0, stream>>>(dw3, dw5, dw7, ws);
  kEm<<<B * K * 4, 256, 0, stream>>>(ws, ws);
  kFm<<<dim3(HW / 64, 1, B), 256, 0, stream>>>(x, pw_b, ws, out);
}

// Round 2
// 622.295 us; speedup vs baseline: 1.0435x; 1.0400x over previous
//
#include <hip/hip_runtime.h>
#include <math.h>

// Problem constants
constexpr int B  = 8;
constexpr int C  = 256;   // Cin
constexpr int M  = 256;
constexpr int O  = 256;
constexpr int H  = 128;
constexpr int W  = 128;
constexpr int HW = H * W; // 16384
constexpr int K  = 128;   // top-k / kept channels

using f16   = _Float16;
using f16x2 = __attribute__((ext_vector_type(2))) _Float16;
using f16x8 = __attribute__((ext_vector_type(8))) _Float16;
using f32x4 = __attribute__((ext_vector_type(4))) float;

// Workspace layout (offsets in float units)
constexpr size_t WS_MEANX = 0;        // 2048
constexpr size_t WS_MASK  = 2048;     // 2048
constexpr size_t WS_G2    = 4096;     // 2048
constexpr size_t WS_OFF   = 6144;     // 48 (pad to 64)
constexpr size_t WS_WE3   = 6208;     // 9216
constexpr size_t WS_WE5   = 15424;    // 25600
constexpr size_t WS_WE7   = 41024;    // 50176
constexpr size_t WS_WT1G  = 91200;    // 65536 f16 (pw1_w fragment-linear)
constexpr size_t WS_WT2G  = 123968;   // 98304 f16 (pw_w[:, :384] fragment-linear)
constexpr size_t WS_SELH  = 173120;   // B*K*HW f16 = 8388608 float slots (33.5 MB)
// BIG region: union of xh (B*C*HW f16 = 16777216 slots, dead after kCm)
//             and yh2 (3*B*K*HW f16 = 25165824 slots, written by kEm after kCm)
constexpr size_t WS_BIG   = 8561728;
// end = 33727552 floats = 134.91 MB (same proven footprint as before)

// ---------------------------------------------------------------------------
// Kernel T: fragment-linear f16 weight copies + zero meanx/gap2sum.
// wt1g index = ((ks*16 + fr)*64 + l)*8 + j  ->  pw1_w[o=fr*16+(l&15)][c=ks*32+(l>>4)*8+j]
// wt2g same with 12 k-steps over pw_w[:, :384].
// ---------------------------------------------------------------------------
__global__ __launch_bounds__(256) void kT(const float* __restrict__ pw1_w,
                                          const float* __restrict__ pw_w,
                                          float* __restrict__ ws) {
  f16* wt1g = (f16*)(ws + WS_WT1G);
  f16* wt2g = (f16*)(ws + WS_WT2G);
  int t = blockIdx.x * 256 + threadIdx.x;
  if (t < 65536) {
    int ks = t >> 13, fr = (t >> 9) & 15, l = (t >> 3) & 63, j = t & 7;
    int o = fr * 16 + (l & 15);
    int c = ks * 32 + ((l >> 4) << 3) + j;
    wt1g[t] = (f16)pw1_w[o * C + c];
  }
  if (t < 98304) {
    int ks = t >> 13, fr = (t >> 9) & 15, l = (t >> 3) & 63, j = t & 7;
    int o = fr * 16 + (l & 15);
    int cc = ks * 32 + ((l >> 4) << 3) + j;
    wt2g[t] = (f16)pw_w[(size_t)o * 768 + cc];
  }
  if (t < 2048) {
    ws[WS_MEANX + t] = 0.f;
    ws[WS_G2 + t]    = 0.f;
  }
}

// ---------------------------------------------------------------------------
// Kernel AT: read x once; emit per-channel means (atomic partials) and xh =
// f16 x in octet-interleaved layout xh[((b*32+ko)*HW + p)*8 + j], k = 8ko+j.
// LDS 8x256 f32 tile transpose: both global sides fully coalesced.
// ---------------------------------------------------------------------------
__global__ __launch_bounds__(256) void kAT(const float* __restrict__ x,
                                           float* __restrict__ ws) {
  float* meanx = ws + WS_MEANX;
  f16* xh      = (f16*)(ws + WS_BIG);
  int b = blockIdx.z, ko = blockIdx.y, p0 = blockIdx.x * 256;
  __shared__ float sx[8][256];
  int t = threadIdx.x;
  int c8 = t >> 5, pg = t & 31;
  const float* xp = x + (size_t)(b * 256 + ko * 8 + c8) * HW + p0 + pg * 8;
  float4 v0 = ((const float4*)xp)[0];
  float4 v1 = ((const float4*)xp)[1];
  *(float4*)&sx[c8][pg * 8]     = v0;
  *(float4*)&sx[c8][pg * 8 + 4] = v1;
  float s = v0.x + v0.y + v0.z + v0.w + v1.x + v1.y + v1.z + v1.w;
#pragma unroll
  for (int off = 16; off > 0; off >>= 1) s += __shfl_xor(s, off, 32);
  if (pg == 0) atomicAdd(&meanx[b * 256 + ko * 8 + c8], s * (1.f / HW));
  __syncthreads();
  f16x8 o;
#pragma unroll
  for (int j = 0; j < 8; j++) o[j] = (f16)sx[j][t];
  *(f16x8*)&xh[((size_t)(b * 32 + ko) * HW + p0 + t) * 8] = o;
}

// ---------------------------------------------------------------------------
// Kernel B: per-batch block; exact fp32 scoring path (unchanged).
// ---------------------------------------------------------------------------
__global__ __launch_bounds__(256) void kB(const float* __restrict__ pw1_w,
                                          const float* __restrict__ pw1_b,
                                          const float* __restrict__ fc1_w,
                                          const float* __restrict__ fc1_b,
                                          const float* __restrict__ fc2_w,
                                          const float* __restrict__ fc2_b,
                                          float* __restrict__ ws) {
  int b = blockIdx.x;
  const float* meanx = ws + WS_MEANX + b * C;
  float* maskg = ws + WS_MASK;
  __shared__ float s_gap[M];
  __shared__ float s_hid[512];
  __shared__ float s_sc[M];
  int t = threadIdx.x;
  int lane = t & 63, wv = t >> 6;

  float4 mx = ((const float4*)meanx)[lane];
  for (int o0 = wv * 64; o0 < wv * 64 + 64; o0 += 4) {
    float s[4];
#pragma unroll
    for (int j = 0; j < 4; j++) {
      float4 w = ((const float4*)(pw1_w + (size_t)(o0 + j) * C))[lane];
      s[j] = mx.x * w.x + mx.y * w.y + mx.z * w.z + mx.w * w.w;
    }
#pragma unroll
    for (int off = 32; off > 0; off >>= 1)
#pragma unroll
      for (int j = 0; j < 4; j++) s[j] += __shfl_xor(s[j], off, 64);
    if (lane == 0) {
#pragma unroll
      for (int j = 0; j < 4; j++) s_gap[o0 + j] = s[j] + pw1_b[o0 + j];
    }
  }
  __syncthreads();

  float4 g4 = ((const float4*)s_gap)[lane];
  for (int j0 = wv * 128; j0 < wv * 128 + 128; j0 += 4) {
    float s[4];
#pragma unroll
    for (int j = 0; j < 4; j++) {
      float4 w = ((const float4*)(fc1_w + (size_t)(j0 + j) * M))[lane];
      s[j] = g4.x * w.x + g4.y * w.y + g4.z * w.z + g4.w * w.w;
    }
#pragma unroll
    for (int off = 32; off > 0; off >>= 1)
#pragma unroll
      for (int j = 0; j < 4; j++) s[j] += __shfl_xor(s[j], off, 64);
    if (lane == 0) {
#pragma unroll
      for (int j = 0; j < 4; j++) {
        float v = s[j] + fc1_b[j0 + j];
        s_hid[j0 + j] = v > 0.f ? v : 0.f;
      }
    }
  }
  __syncthreads();

  float4 h0 = ((const float4*)s_hid)[lane];
  float4 h1 = ((const float4*)s_hid)[lane + 64];
  for (int o0 = wv * 64; o0 < wv * 64 + 64; o0 += 4) {
    float s[4];
#pragma unroll
    for (int j = 0; j < 4; j++) {
      const float4* wr = (const float4*)(fc2_w + (size_t)(o0 + j) * 512);
      float4 w0 = wr[lane];
      float4 w1 = wr[lane + 64];
      s[j] = h0.x * w0.x + h0.y * w0.y + h0.z * w0.z + h0.w * w0.w +
             h1.x * w1.x + h1.y * w1.y + h1.z * w1.z + h1.w * w1.w;
    }
#pragma unroll
    for (int off = 32; off > 0; off >>= 1)
#pragma unroll
      for (int j = 0; j < 4; j++) s[j] += __shfl_xor(s[j], off, 64);
    if (lane == 0) {
#pragma unroll
      for (int j = 0; j < 4; j++) {
        float v = s[j] + fc2_b[o0 + j];
        s_sc[o0 + j] = 1.f / (1.f + expf(-v));
      }
    }
  }
  __syncthreads();

  {
    int j = t;
    float sj = s_sc[j];
    int cnt = 0;
    for (int m = 0; m < M; m++) {
      float sm = s_sc[m];
      cnt += (sm > sj) || (sm == sj && m < j);
    }
    maskg[b * M + j] = (cnt < K) ? 1.f : 0.f;
  }
}

// ---------------------------------------------------------------------------
// Kernel Cm: h = relu(pw1(x)) via f16 MFMA. Barrier-free, LDS-free:
// A = wt1g fragment-linear (1KB/wave coalesced), B = xh octet-interleaved
// (single f16x8 global load per lane per fragment). 8 k-steps of 32.
// ---------------------------------------------------------------------------
__global__ __launch_bounds__(256) void kCm(const float* __restrict__ pw1_b,
                                           float* __restrict__ ws) {
  const f16* wt1g = (const f16*)(ws + WS_WT1G);
  const f16* xh   = (const f16*)(ws + WS_BIG);
  float* gap2sum  = ws + WS_G2;
  f16* selh       = (f16*)(ws + WS_SELH);
  int b  = blockIdx.z;
  int p0 = blockIdx.x * 64;

  int t = threadIdx.x, l = t & 63, w = t >> 6;
  int q = l >> 4, n = l & 15;

  f32x4 acc[4][4];
#pragma unroll
  for (int i = 0; i < 4; i++)
#pragma unroll
    for (int j = 0; j < 4; j++)
#pragma unroll
      for (int r = 0; r < 4; r++) acc[i][j][r] = 0.f;

  const f16* bbase = xh + (size_t)(b * 32 + q) * (HW * 8) + (size_t)(p0 + n) * 8;
  const f16* abase = wt1g + (size_t)(w * 4) * 512 + (size_t)l * 8;

#pragma unroll 2
  for (int ks = 0; ks < 8; ks++) {
    f16x8 afr[4], bfr[4];
#pragma unroll
    for (int mt = 0; mt < 4; mt++)
      afr[mt] = *(const f16x8*)(abase + (size_t)(ks * 16 + mt) * 512);
#pragma unroll
    for (int nt = 0; nt < 4; nt++)
      bfr[nt] = *(const f16x8*)(bbase + (size_t)ks * (4 * HW * 8) + nt * 128);
#pragma unroll
    for (int mt = 0; mt < 4; mt++)
#pragma unroll
      for (int nt = 0; nt < 4; nt++)
        acc[mt][nt] = __builtin_amdgcn_mfma_f32_16x16x32_f16(afr[mt], bfr[nt],
                                                             acc[mt][nt], 0, 0, 0);
  }

  // Epilogue: bias + relu; sel f16 store (o<128); gap2sum partial sums
#pragma unroll
  for (int mt = 0; mt < 4; mt++) {
    float rsum[4] = {0.f, 0.f, 0.f, 0.f};
    int obase = w * 64 + mt * 16 + q * 4;
    float bias[4];
#pragma unroll
    for (int r = 0; r < 4; r++) bias[r] = pw1_b[obase + r];
#pragma unroll
    for (int nt = 0; nt < 4; nt++) {
      int p = p0 + nt * 16 + n;
#pragma unroll
      for (int r = 0; r < 4; r++) {
        float h = acc[mt][nt][r] + bias[r];
        h = h > 0.f ? h : 0.f;
        rsum[r] += h;
        int o = obase + r;
        if (o < K) selh[((size_t)(b * K + o)) * HW + p] = (f16)h;
      }
    }
#pragma unroll
    for (int off = 1; off < 16; off <<= 1)
#pragma unroll
      for (int r = 0; r < 4; r++) rsum[r] += __shfl_xor(rsum[r], off, 64);
    if (n == 0) {
#pragma unroll
      for (int r = 0; r < 4; r++)
        atomicAdd(&gap2sum[b * M + obase + r], rsum[r]);
    }
  }
}

// ---------------------------------------------------------------------------
// Kernel D1 (1 block): offsets from gap2; emit per-(b,branch) scale/shift.
// ---------------------------------------------------------------------------
__global__ __launch_bounds__(256) void kD1(const float* __restrict__ off_w,
                                           const float* __restrict__ off_b,
                                           float* __restrict__ ws) {
  const float* gap2sum = ws + WS_G2;
  float* offv = ws + WS_OFF;  // [0..23]=scale(b*3+i), [24..47]=shift
  __shared__ float s_off[48];
  int t = threadIdx.x;
  int lane = t & 63, wv = t >> 6;
  for (int id = wv; id < 48; id += 4) {
    int b = id / 6, j = id % 6;
    float4 g = ((const float4*)(gap2sum + b * M))[lane];
    float4 w = ((const float4*)(off_w + (size_t)j * M))[lane];
    float s = (g.x * w.x + g.y * w.y + g.z * w.z + g.w * w.w) * (1.f / HW);
#pragma unroll
    for (int off = 32; off > 0; off >>= 1) s += __shfl_xor(s, off, 64);
    if (lane == 0) s_off[id] = tanhf(s + off_b[j]);
  }
  __syncthreads();
  if (t < 24) {
    int b = t / 3, i = t % 3;
    offv[t]      = 1.f + 1.f / (1.f + expf(-s_off[b * 6 + 2 * i]));
    offv[24 + t] = tanhf(s_off[b * 6 + 2 * i + 1]);
  }
}

// ---------------------------------------------------------------------------
// Kernel D2: effective depthwise weights, with top-k mask folded in.
// ---------------------------------------------------------------------------
__global__ __launch_bounds__(256) void kD2(const float* __restrict__ dw3,
                                           const float* __restrict__ dw5,
                                           const float* __restrict__ dw7,
                                           float* __restrict__ ws) {
  const float* offv  = ws + WS_OFF;
  const float* maskg = ws + WS_MASK;
  float* wE3 = ws + WS_WE3;
  float* wE5 = ws + WS_WE5;
  float* wE7 = ws + WS_WE7;
  int tid = blockIdx.x * 256 + threadIdx.x;
  int stride = gridDim.x * 256;
  for (int i = tid; i < B * K * 9; i += stride) {
    int b = i / (K * 9), rem = i % (K * 9), c = rem / 9;
    wE3[i] = (dw3[rem] * offv[b * 3 + 0] + offv[24 + b * 3 + 0]) * maskg[b * M + c];
  }
  for (int i = tid; i < B * K * 25; i += stride) {
    int b = i / (K * 25), rem = i % (K * 25), c = rem / 25;
    wE5[i] = (dw5[rem] * offv[b * 3 + 1] + offv[24 + b * 3 + 1]) * maskg[b * M + c];
  }
  for (int i = tid; i < B * K * 49; i += stride) {
    int b = i / (K * 49), rem = i % (K * 49), c = rem / 49;
    wE7[i] = (dw7[rem] * offv[b * 3 + 2] + offv[24 + b * 3 + 2]) * maskg[b * M + c];
  }
}

// ---------------------------------------------------------------------------
// Kernel Em: merged depthwise conv, 8 channels/block so writes to the
// octet-interleaved yh2 layout are contiguous. f16 halo in LDS; paired
// ds_read_b32 taps (2 output cols per thread); 3 branches sequential.
// Block: 256 thr = 8 ch x 32 col-pairs (64 cols). Grid: (8 slabs x 2 halves,
// 16 ko, 8 b). yh2[((b*48 + br*16 + ko)*HW + p)*8 + ch].
// ---------------------------------------------------------------------------
__global__ __launch_bounds__(256) void kEm(const float* __restrict__ ws_ro,
                                           float* __restrict__ ws) {
  // per-channel halo plane: 22 rows x 72 cols (70 used), stride keeps
  // paired-b32 reads at 2-way (free) bank aliasing.
  __shared__ f16 sm[8 * 22 * 72];  // 25344 B
  const f16* selh = (const f16*)(ws_ro + WS_SELH);
  f16* yh2        = (f16*)(ws + WS_BIG);
  int bx = blockIdx.x;
  int slab = bx >> 1, chalf = bx & 1;
  int ko = blockIdx.y, b = blockIdx.z;
  int r0 = slab * 16, c0 = chalf * 64;

  for (int i = threadIdx.x; i < 8 * 1584; i += 256) {
    int chn = i / 1584, rem = i - chn * 1584;
    int rr = rem / 72, cc = rem - rr * 72;
    int gy = r0 - 3 + rr, gx = c0 - 3 + cc;
    f16 v = (f16)0.f;
    if (gy >= 0 && gy < H && gx >= 0 && gx < W)
      v = selh[(size_t)(b * 128 + ko * 8 + chn) * HW + gy * W + gx];
    sm[i] = v;
  }
  __syncthreads();

  int t = threadIdx.x;
  int ch = t & 7, cp = t >> 3;  // channel 0..7, col-pair 0..31
  int cglob = c0 + cp * 2;      // first of 2 output cols

#define CONV_BRANCH(KS, BR, WSOFF, NW, WSHIFT)                                 \
  {                                                                            \
    constexpr int P = (KS - 1) / 2;                                            \
    const float* wp = ws_ro + WSOFF + (size_t)(b * 128 + ko * 8 + ch) * (KS*KS); \
    float w[KS * KS];                                                          \
    _Pragma("unroll") for (int i = 0; i < KS * KS; i++) w[i] = wp[i];          \
    float a0[16], a1[16];                                                      \
    _Pragma("unroll") for (int r = 0; r < 16; r++) { a0[r] = 0.f; a1[r] = 0.f; } \
    _Pragma("unroll") for (int iy = 0; iy < 16 + 2 * P; iy++) {                \
      int hr = iy + 3 - P;                                                     \
      const f16x2* rowp = (const f16x2*)(sm + ch * 1584 + hr * 72);            \
      float vv[2 * NW];                                                        \
      _Pragma("unroll") for (int u = 0; u < NW; u++) {                         \
        f16x2 pr = rowp[cp + WSHIFT + u];                                      \
        vv[2 * u]     = (float)pr[0];                                          \
        vv[2 * u + 1] = (float)pr[1];                                          \
      }                                                                        \
      _Pragma("unroll") for (int rr = 0; rr < 16; rr++) {                      \
        int dy = iy - rr;                                                      \
        if (dy >= 0 && dy < KS) {                                              \
          _Pragma("unroll") for (int dx = 0; dx < KS; dx++) {                  \
            int m = (3 - P) + dx - 2 * WSHIFT;                                 \
            a0[rr] += vv[m]     * w[dy * KS + dx];                             \
            a1[rr] += vv[m + 1] * w[dy * KS + dx];                             \
          }                                                                    \
        }                                                                      \
      }                                                                        \
    }                                                                          \
    f16* op = yh2 + (size_t)(b * 48 + BR * 16 + ko) * HW * 8;                  \
    _Pragma("unroll") for (int rr = 0; rr < 16; rr++) {                        \
      size_t pa = ((size_t)(r0 + rr) * W + cglob) * 8 + ch;                    \
      op[pa]     = (f16)a0[rr];                                                \
      op[pa + 8] = (f16)a1[rr];                                                \
    }                                                                          \
  }

  CONV_BRANCH(3, 0, WS_WE3, 2, 1)
  CONV_BRANCH(5, 1, WS_WE5, 4, 0)
  CONV_BRANCH(7, 2, WS_WE7, 4, 0)
#undef CONV_BRANCH
}

// ---------------------------------------------------------------------------
// Kernel Fm: merged final pointwise, f16 MFMA, K=384. Barrier-free, LDS-free:
// A = wt2g fragment-linear, B = yh2 octet-interleaved. 12 k-steps of 32.
// Epilogue: + pw_b + residual x.
// ---------------------------------------------------------------------------
__global__ __launch_bounds__(256) void kFm(const float* __restrict__ x,
                                           const float* __restrict__ pw_b,
                                           const float* __restrict__ ws,
                                           float* __restrict__ out) {
  const f16* wt2g = (const f16*)(ws + WS_WT2G);
  const f16* yh2  = (const f16*)(ws + WS_BIG);
  int b  = blockIdx.z;
  int p0 = blockIdx.x * 64;

  int t = threadIdx.x, l = t & 63, w = t >> 6;
  int q = l >> 4, n = l & 15;

  f32x4 acc[4][4];
#pragma unroll
  for (int i = 0; i < 4; i++)
#pragma unroll
    for (int j = 0; j < 4; j++)
#pragma unroll
      for (int r = 0; r < 4; r++) acc[i][j][r] = 0.f;

  const f16* bbase = yh2 + (size_t)(b * 48 + q) * (HW * 8) + (size_t)(p0 + n) * 8;
  const f16* abase = wt2g + (size_t)(w * 4) * 512 + (size_t)l * 8;

#pragma unroll 2
  for (int ks = 0; ks < 12; ks++) {
    f16x8 afr[4], bfr[4];
#pragma unroll
    for (int mt = 0; mt < 4; mt++)
      afr[mt] = *(const f16x8*)(abase + (size_t)(ks * 16 + mt) * 512);
#pragma unroll
    for (int nt = 0; nt < 4; nt++)
      bfr[nt] = *(const f16x8*)(bbase + (size_t)ks * (4 * HW * 8) + nt * 128);
#pragma unroll
    for (int mt = 0; mt < 4; mt++)
#pragma unroll
      for (int nt = 0; nt < 4; nt++)
        acc[mt][nt] = __builtin_amdgcn_mfma_f32_16x16x32_f16(afr[mt], bfr[nt],
                                                             acc[mt][nt], 0, 0, 0);
  }

#pragma unroll
  for (int mt = 0; mt < 4; mt++) {
    int obase = w * 64 + mt * 16 + q * 4;
    float bias[4];
#pragma unroll
    for (int r = 0; r < 4; r++) bias[r] = pw_b[obase + r];
#pragma unroll
    for (int nt = 0; nt < 4; nt++) {
      int p = p0 + nt * 16 + n;
#pragma unroll
      for (int r = 0; r < 4; r++) {
        size_t idx = ((size_t)b * O + obase + r) * HW + p;
        out[idx] = acc[mt][nt][r] + bias[r] + x[idx];
      }
    }
  }
}

// ---------------------------------------------------------------------------
extern "C" void kernel_launch(void* const* d_in, const int* in_sizes, int n_in,
                              void* d_out, int out_size, void* d_ws, size_t ws_size,
                              hipStream_t stream) {
  const float* x     = (const float*)d_in[0];
  const float* pw1_w = (const float*)d_in[1];
  const float* pw1_b = (const float*)d_in[2];
  const float* fc1_w = (const float*)d_in[3];
  const float* fc1_b = (const float*)d_in[4];
  const float* fc2_w = (const float*)d_in[5];
  const float* fc2_b = (const float*)d_in[6];
  const float* off_w = (const float*)d_in[7];
  const float* off_b = (const float*)d_in[8];
  const float* dw3   = (const float*)d_in[9];
  const float* dw5   = (const float*)d_in[10];
  const float* dw7   = (const float*)d_in[11];
  const float* pw_w  = (const float*)d_in[12];
  const float* pw_b  = (const float*)d_in[13];
  float* out = (float*)d_out;
  float* ws  = (float*)d_ws;

  kT<<<384, 256, 0, stream>>>(pw1_w, pw_w, ws);
  kAT<<<dim3(HW / 256, 32, B), 256, 0, stream>>>(x, ws);
  kB<<<B, 256, 0, stream>>>(pw1_w, pw1_b, fc1_w, fc1_b, fc2_w, fc2_b, ws);
  kCm<<<dim3(HW / 64, 1, B), 256, 0, stream>>>(pw1_b, ws);
  kD1<<<1, 256, 0, stream>>>(off_w, off_b, ws);
  kD2<<<84, 256, 0, stream>>>(dw3, dw5, dw7, ws);
  kEm<<<dim3(16, 16, B), 256, 0, stream>>>(ws, ws);
  kFm<<<dim3(HW / 64, 1, B), 256, 0, stream>>>(x, pw_b, ws, out);
}

// Round 3
// 617.369 us; speedup vs baseline: 1.0518x; 1.0080x over previous
//
#include <hip/hip_runtime.h>
#include <math.h>

// Problem constants
constexpr int B  = 8;
constexpr int C  = 256;   // Cin
constexpr int M  = 256;
constexpr int O  = 256;
constexpr int H  = 128;
constexpr int W  = 128;
constexpr int HW = H * W; // 16384
constexpr int K  = 128;   // top-k / kept channels

using f16   = _Float16;
using f16x2 = __attribute__((ext_vector_type(2))) _Float16;
using f16x8 = __attribute__((ext_vector_type(8))) _Float16;
using f32x4 = __attribute__((ext_vector_type(4))) float;

#if __has_builtin(__builtin_amdgcn_fdot2)
#define FDOT2(a, b, c) __builtin_amdgcn_fdot2((a), (b), (c), false)
#else
#define FDOT2(a, b, c) ((c) + (float)(a)[0] * (float)(b)[0] + (float)(a)[1] * (float)(b)[1])
#endif

// Workspace layout (offsets in float units)
constexpr size_t WS_MEANX = 0;        // 2048
constexpr size_t WS_MASK  = 2048;     // 2048
constexpr size_t WS_G2    = 4096;     // 2048
constexpr size_t WS_OFF   = 6144;     // 48 (pad to 64)
constexpr size_t WS_WE3   = 6208;     // 9216
constexpr size_t WS_WE5   = 15424;    // 25600
constexpr size_t WS_WE7   = 41024;    // 50176
constexpr size_t WS_WT1G  = 91200;    // 65536 f16 (pw1_w fragment-linear)
constexpr size_t WS_WT2G  = 123968;   // 98304 f16 (pw_w[:, :384] fragment-linear)
constexpr size_t WS_SELH  = 173120;   // B*K*HW f16 = 8388608 float slots (33.5 MB)
// BIG region: union of xh (B*C*HW f16, dead after kCm) and yh2 (3*B*K*HW f16)
constexpr size_t WS_BIG   = 8561728;
// end = 33727552 floats = 134.91 MB (same proven footprint as before)

// ---------------------------------------------------------------------------
// Kernel T: fragment-linear f16 weight copies + zero meanx/gap2sum.
// ---------------------------------------------------------------------------
__global__ __launch_bounds__(256) void kT(const float* __restrict__ pw1_w,
                                          const float* __restrict__ pw_w,
                                          float* __restrict__ ws) {
  f16* wt1g = (f16*)(ws + WS_WT1G);
  f16* wt2g = (f16*)(ws + WS_WT2G);
  int t = blockIdx.x * 256 + threadIdx.x;
  if (t < 65536) {
    int ks = t >> 13, fr = (t >> 9) & 15, l = (t >> 3) & 63, j = t & 7;
    int o = fr * 16 + (l & 15);
    int c = ks * 32 + ((l >> 4) << 3) + j;
    wt1g[t] = (f16)pw1_w[o * C + c];
  }
  if (t < 98304) {
    int ks = t >> 13, fr = (t >> 9) & 15, l = (t >> 3) & 63, j = t & 7;
    int o = fr * 16 + (l & 15);
    int cc = ks * 32 + ((l >> 4) << 3) + j;
    wt2g[t] = (f16)pw_w[(size_t)o * 768 + cc];
  }
  if (t < 2048) {
    ws[WS_MEANX + t] = 0.f;
    ws[WS_G2 + t]    = 0.f;
  }
}

// ---------------------------------------------------------------------------
// Kernel AT: read x once; per-channel means (atomic partials) and xh = f16 x
// in octet-interleaved layout xh[((b*32+ko)*HW + p)*8 + j], k = 8ko+j.
// ---------------------------------------------------------------------------
__global__ __launch_bounds__(256) void kAT(const float* __restrict__ x,
                                           float* __restrict__ ws) {
  float* meanx = ws + WS_MEANX;
  f16* xh      = (f16*)(ws + WS_BIG);
  int b = blockIdx.z, ko = blockIdx.y, p0 = blockIdx.x * 256;
  __shared__ float sx[8][256];
  int t = threadIdx.x;
  int c8 = t >> 5, pg = t & 31;
  const float* xp = x + (size_t)(b * 256 + ko * 8 + c8) * HW + p0 + pg * 8;
  float4 v0 = ((const float4*)xp)[0];
  float4 v1 = ((const float4*)xp)[1];
  *(float4*)&sx[c8][pg * 8]     = v0;
  *(float4*)&sx[c8][pg * 8 + 4] = v1;
  float s = v0.x + v0.y + v0.z + v0.w + v1.x + v1.y + v1.z + v1.w;
#pragma unroll
  for (int off = 16; off > 0; off >>= 1) s += __shfl_xor(s, off, 32);
  if (pg == 0) atomicAdd(&meanx[b * 256 + ko * 8 + c8], s * (1.f / HW));
  __syncthreads();
  f16x8 o;
#pragma unroll
  for (int j = 0; j < 8; j++) o[j] = (f16)sx[j][t];
  *(f16x8*)&xh[((size_t)(b * 32 + ko) * HW + p0 + t) * 8] = o;
}

// ---------------------------------------------------------------------------
// Kernel B: per-batch block; exact fp32 scoring path (unchanged).
// ---------------------------------------------------------------------------
__global__ __launch_bounds__(256) void kB(const float* __restrict__ pw1_w,
                                          const float* __restrict__ pw1_b,
                                          const float* __restrict__ fc1_w,
                                          const float* __restrict__ fc1_b,
                                          const float* __restrict__ fc2_w,
                                          const float* __restrict__ fc2_b,
                                          float* __restrict__ ws) {
  int b = blockIdx.x;
  const float* meanx = ws + WS_MEANX + b * C;
  float* maskg = ws + WS_MASK;
  __shared__ float s_gap[M];
  __shared__ float s_hid[512];
  __shared__ float s_sc[M];
  int t = threadIdx.x;
  int lane = t & 63, wv = t >> 6;

  float4 mx = ((const float4*)meanx)[lane];
  for (int o0 = wv * 64; o0 < wv * 64 + 64; o0 += 4) {
    float s[4];
#pragma unroll
    for (int j = 0; j < 4; j++) {
      float4 w = ((const float4*)(pw1_w + (size_t)(o0 + j) * C))[lane];
      s[j] = mx.x * w.x + mx.y * w.y + mx.z * w.z + mx.w * w.w;
    }
#pragma unroll
    for (int off = 32; off > 0; off >>= 1)
#pragma unroll
      for (int j = 0; j < 4; j++) s[j] += __shfl_xor(s[j], off, 64);
    if (lane == 0) {
#pragma unroll
      for (int j = 0; j < 4; j++) s_gap[o0 + j] = s[j] + pw1_b[o0 + j];
    }
  }
  __syncthreads();

  float4 g4 = ((const float4*)s_gap)[lane];
  for (int j0 = wv * 128; j0 < wv * 128 + 128; j0 += 4) {
    float s[4];
#pragma unroll
    for (int j = 0; j < 4; j++) {
      float4 w = ((const float4*)(fc1_w + (size_t)(j0 + j) * M))[lane];
      s[j] = g4.x * w.x + g4.y * w.y + g4.z * w.z + g4.w * w.w;
    }
#pragma unroll
    for (int off = 32; off > 0; off >>= 1)
#pragma unroll
      for (int j = 0; j < 4; j++) s[j] += __shfl_xor(s[j], off, 64);
    if (lane == 0) {
#pragma unroll
      for (int j = 0; j < 4; j++) {
        float v = s[j] + fc1_b[j0 + j];
        s_hid[j0 + j] = v > 0.f ? v : 0.f;
      }
    }
  }
  __syncthreads();

  float4 h0 = ((const float4*)s_hid)[lane];
  float4 h1 = ((const float4*)s_hid)[lane + 64];
  for (int o0 = wv * 64; o0 < wv * 64 + 64; o0 += 4) {
    float s[4];
#pragma unroll
    for (int j = 0; j < 4; j++) {
      const float4* wr = (const float4*)(fc2_w + (size_t)(o0 + j) * 512);
      float4 w0 = wr[lane];
      float4 w1 = wr[lane + 64];
      s[j] = h0.x * w0.x + h0.y * w0.y + h0.z * w0.z + h0.w * w0.w +
             h1.x * w1.x + h1.y * w1.y + h1.z * w1.z + h1.w * w1.w;
    }
#pragma unroll
    for (int off = 32; off > 0; off >>= 1)
#pragma unroll
      for (int j = 0; j < 4; j++) s[j] += __shfl_xor(s[j], off, 64);
    if (lane == 0) {
#pragma unroll
      for (int j = 0; j < 4; j++) {
        float v = s[j] + fc2_b[o0 + j];
        s_sc[o0 + j] = 1.f / (1.f + expf(-v));
      }
    }
  }
  __syncthreads();

  {
    int j = t;
    float sj = s_sc[j];
    int cnt = 0;
    for (int m = 0; m < M; m++) {
      float sm = s_sc[m];
      cnt += (sm > sj) || (sm == sj && m < j);
    }
    maskg[b * M + j] = (cnt < K) ? 1.f : 0.f;
  }
}

// ---------------------------------------------------------------------------
// Kernel Cm: h = relu(pw1(x)) via f16 MFMA. Barrier-free, LDS-free.
// ---------------------------------------------------------------------------
__global__ __launch_bounds__(256) void kCm(const float* __restrict__ pw1_b,
                                           float* __restrict__ ws) {
  const f16* wt1g = (const f16*)(ws + WS_WT1G);
  const f16* xh   = (const f16*)(ws + WS_BIG);
  float* gap2sum  = ws + WS_G2;
  f16* selh       = (f16*)(ws + WS_SELH);
  int b  = blockIdx.z;
  int p0 = blockIdx.x * 64;

  int t = threadIdx.x, l = t & 63, w = t >> 6;
  int q = l >> 4, n = l & 15;

  f32x4 acc[4][4];
#pragma unroll
  for (int i = 0; i < 4; i++)
#pragma unroll
    for (int j = 0; j < 4; j++)
#pragma unroll
      for (int r = 0; r < 4; r++) acc[i][j][r] = 0.f;

  const f16* bbase = xh + (size_t)(b * 32 + q) * (HW * 8) + (size_t)(p0 + n) * 8;
  const f16* abase = wt1g + (size_t)(w * 4) * 512 + (size_t)l * 8;

#pragma unroll 2
  for (int ks = 0; ks < 8; ks++) {
    f16x8 afr[4], bfr[4];
#pragma unroll
    for (int mt = 0; mt < 4; mt++)
      afr[mt] = *(const f16x8*)(abase + (size_t)(ks * 16 + mt) * 512);
#pragma unroll
    for (int nt = 0; nt < 4; nt++)
      bfr[nt] = *(const f16x8*)(bbase + (size_t)ks * (4 * HW * 8) + nt * 128);
#pragma unroll
    for (int mt = 0; mt < 4; mt++)
#pragma unroll
      for (int nt = 0; nt < 4; nt++)
        acc[mt][nt] = __builtin_amdgcn_mfma_f32_16x16x32_f16(afr[mt], bfr[nt],
                                                             acc[mt][nt], 0, 0, 0);
  }

  // Epilogue: bias + relu; sel f16 store (o<128); gap2sum partial sums
#pragma unroll
  for (int mt = 0; mt < 4; mt++) {
    float rsum[4] = {0.f, 0.f, 0.f, 0.f};
    int obase = w * 64 + mt * 16 + q * 4;
    float bias[4];
#pragma unroll
    for (int r = 0; r < 4; r++) bias[r] = pw1_b[obase + r];
#pragma unroll
    for (int nt = 0; nt < 4; nt++) {
      int p = p0 + nt * 16 + n;
#pragma unroll
      for (int r = 0; r < 4; r++) {
        float h = acc[mt][nt][r] + bias[r];
        h = h > 0.f ? h : 0.f;
        rsum[r] += h;
        int o = obase + r;
        if (o < K) selh[((size_t)(b * K + o)) * HW + p] = (f16)h;
      }
    }
#pragma unroll
    for (int off = 1; off < 16; off <<= 1)
#pragma unroll
      for (int r = 0; r < 4; r++) rsum[r] += __shfl_xor(rsum[r], off, 64);
    if (n == 0) {
#pragma unroll
      for (int r = 0; r < 4; r++)
        atomicAdd(&gap2sum[b * M + obase + r], rsum[r]);
    }
  }
}

// ---------------------------------------------------------------------------
// Kernel D1 (1 block): offsets from gap2; emit per-(b,branch) scale/shift.
// ---------------------------------------------------------------------------
__global__ __launch_bounds__(256) void kD1(const float* __restrict__ off_w,
                                           const float* __restrict__ off_b,
                                           float* __restrict__ ws) {
  const float* gap2sum = ws + WS_G2;
  float* offv = ws + WS_OFF;  // [0..23]=scale(b*3+i), [24..47]=shift
  __shared__ float s_off[48];
  int t = threadIdx.x;
  int lane = t & 63, wv = t >> 6;
  for (int id = wv; id < 48; id += 4) {
    int b = id / 6, j = id % 6;
    float4 g = ((const float4*)(gap2sum + b * M))[lane];
    float4 w = ((const float4*)(off_w + (size_t)j * M))[lane];
    float s = (g.x * w.x + g.y * w.y + g.z * w.z + g.w * w.w) * (1.f / HW);
#pragma unroll
    for (int off = 32; off > 0; off >>= 1) s += __shfl_xor(s, off, 64);
    if (lane == 0) s_off[id] = tanhf(s + off_b[j]);
  }
  __syncthreads();
  if (t < 24) {
    int b = t / 3, i = t % 3;
    offv[t]      = 1.f + 1.f / (1.f + expf(-s_off[b * 6 + 2 * i]));
    offv[24 + t] = tanhf(s_off[b * 6 + 2 * i + 1]);
  }
}

// ---------------------------------------------------------------------------
// Kernel D2: effective depthwise weights, with top-k mask folded in.
// ---------------------------------------------------------------------------
__global__ __launch_bounds__(256) void kD2(const float* __restrict__ dw3,
                                           const float* __restrict__ dw5,
                                           const float* __restrict__ dw7,
                                           float* __restrict__ ws) {
  const float* offv  = ws + WS_OFF;
  const float* maskg = ws + WS_MASK;
  float* wE3 = ws + WS_WE3;
  float* wE5 = ws + WS_WE5;
  float* wE7 = ws + WS_WE7;
  int tid = blockIdx.x * 256 + threadIdx.x;
  int stride = gridDim.x * 256;
  for (int i = tid; i < B * K * 9; i += stride) {
    int b = i / (K * 9), rem = i % (K * 9), c = rem / 9;
    wE3[i] = (dw3[rem] * offv[b * 3 + 0] + offv[24 + b * 3 + 0]) * maskg[b * M + c];
  }
  for (int i = tid; i < B * K * 25; i += stride) {
    int b = i / (K * 25), rem = i % (K * 25), c = rem / 25;
    wE5[i] = (dw5[rem] * offv[b * 3 + 1] + offv[24 + b * 3 + 1]) * maskg[b * M + c];
  }
  for (int i = tid; i < B * K * 49; i += stride) {
    int b = i / (K * 49), rem = i % (K * 49), c = rem / 49;
    wE7[i] = (dw7[rem] * offv[b * 3 + 2] + offv[24 + b * 3 + 2]) * maskg[b * M + c];
  }
}

// ---------------------------------------------------------------------------
// Kernel Em: merged depthwise conv via v_dot2_f32_f16.
// - f16 halo in LDS, per-channel stride 1608 f16 (804 dw, %32==4) ->
//   conflict-free b32 f16x2 reads (half-wave covers 32 distinct banks).
// - Weight pairs pre-packed per column parity (shift weights, not data):
//   every dot2 consumes an ALIGNED LDS pair; zero-padded edge pairs are
//   compile-time eliminated. 1568 dot2 vs 2656 scalar FMA + 488 cvt before.
// Block: 256 thr = 8 ch x 32 col-pairs; 16 rows x 64 cols x 8 ch per block.
// ---------------------------------------------------------------------------
__global__ __launch_bounds__(256) void kEm(const float* __restrict__ ws_ro,
                                           float* __restrict__ ws) {
  __shared__ f16 sm[8 * 1608];  // 25728 B
  const f16* selh = (const f16*)(ws_ro + WS_SELH);
  f16* yh2        = (f16*)(ws + WS_BIG);
  int bx = blockIdx.x;
  int slab = bx >> 1, chalf = bx & 1;
  int ko = blockIdx.y, b = blockIdx.z;
  int r0 = slab * 16, c0 = chalf * 64;

  // Fill: logical [8][22][72] (72-col rows, cols 70..71 pad/garbage, never read)
  for (int i = threadIdx.x; i < 8 * 1584; i += 256) {
    int chn = i / 1584, rem = i - chn * 1584;
    int rr = rem / 72, cc = rem - rr * 72;
    int gy = r0 - 3 + rr, gx = c0 - 3 + cc;
    f16 v = (f16)0.f;
    if (gy >= 0 && gy < H && gx >= 0 && gx < W)
      v = selh[(size_t)(b * 128 + ko * 8 + chn) * HW + gy * W + gx];
    sm[chn * 1608 + rem] = v;
  }
  __syncthreads();

  int t = threadIdx.x;
  int ch = t & 7, cp = t >> 3;  // channel 0..7, col-pair 0..31
  int cglob = c0 + cp * 2;

#define CONV_BRANCH(KS, BR, WSOFF, NW, WSHIFT)                                 \
  {                                                                            \
    constexpr int P  = (KS - 1) / 2;                                           \
    constexpr int OE = 3 - P;  /* halo col offset of tap dx=0, even cols */    \
    constexpr int OO = 4 - P;  /* odd cols */                                  \
    const float* wp = ws_ro + WSOFF + (size_t)(b * 128 + ko * 8 + ch) * (KS*KS);\
    f16x2 we[KS][NW], wo[KS][NW];                                              \
    _Pragma("unroll") for (int dy = 0; dy < KS; dy++) {                        \
      f16 wr[KS];                                                              \
      _Pragma("unroll") for (int dx = 0; dx < KS; dx++)                        \
        wr[dx] = (f16)wp[dy * KS + dx];                                        \
      _Pragma("unroll") for (int k = 0; k < NW; k++) {                         \
        int pp0 = 2 * (WSHIFT + k), pp1 = pp0 + 1;                             \
        f16 e0 = (pp0 >= OE && pp0 < OE + KS) ? wr[pp0 - OE] : (f16)0.f;       \
        f16 e1 = (pp1 >= OE && pp1 < OE + KS) ? wr[pp1 - OE] : (f16)0.f;       \
        f16 q0 = (pp0 >= OO && pp0 < OO + KS) ? wr[pp0 - OO] : (f16)0.f;       \
        f16 q1 = (pp1 >= OO && pp1 < OO + KS) ? wr[pp1 - OO] : (f16)0.f;       \
        we[dy][k] = f16x2{e0, e1};                                             \
        wo[dy][k] = f16x2{q0, q1};                                             \
      }                                                                        \
    }                                                                          \
    float a0[16], a1[16];                                                      \
    _Pragma("unroll") for (int r = 0; r < 16; r++) { a0[r] = 0.f; a1[r] = 0.f; } \
    _Pragma("unroll") for (int iy = 0; iy < 16 + 2 * P; iy++) {                \
      int hr = iy + (3 - P);                                                   \
      const f16x2* rowp = (const f16x2*)(sm + ch * 1608 + hr * 72);            \
      f16x2 vv2[NW];                                                           \
      _Pragma("unroll") for (int u = 0; u < NW; u++)                           \
        vv2[u] = rowp[cp + WSHIFT + u];                                        \
      _Pragma("unroll") for (int rr = 0; rr < 16; rr++) {                      \
        int dy = iy - rr;                                                      \
        if (dy >= 0 && dy < KS) {                                              \
          _Pragma("unroll") for (int k = 0; k < NW; k++) {                     \
            int pp0 = 2 * (WSHIFT + k), pp1 = pp0 + 1;                         \
            if (pp1 >= OE && pp0 < OE + KS)                                    \
              a0[rr] = FDOT2(vv2[k], we[dy][k], a0[rr]);                       \
            if (pp1 >= OO && pp0 < OO + KS)                                    \
              a1[rr] = FDOT2(vv2[k], wo[dy][k], a1[rr]);                       \
          }                                                                    \
        }                                                                      \
      }                                                                        \
    }                                                                          \
    f16* op = yh2 + (size_t)(b * 48 + BR * 16 + ko) * HW * 8;                  \
    _Pragma("unroll") for (int rr = 0; rr < 16; rr++) {                        \
      size_t pa = ((size_t)(r0 + rr) * W + cglob) * 8 + ch;                    \
      op[pa]     = (f16)a0[rr];                                                \
      op[pa + 8] = (f16)a1[rr];                                                \
    }                                                                          \
  }

  CONV_BRANCH(3, 0, WS_WE3, 2, 1)
  CONV_BRANCH(5, 1, WS_WE5, 4, 0)
  CONV_BRANCH(7, 2, WS_WE7, 4, 0)
#undef CONV_BRANCH
}

// ---------------------------------------------------------------------------
// Kernel Fm: merged final pointwise, f16 MFMA, K=384. Barrier-free, LDS-free.
// ---------------------------------------------------------------------------
__global__ __launch_bounds__(256) void kFm(const float* __restrict__ x,
                                           const float* __restrict__ pw_b,
                                           const float* __restrict__ ws,
                                           float* __restrict__ out) {
  const f16* wt2g = (const f16*)(ws + WS_WT2G);
  const f16* yh2  = (const f16*)(ws + WS_BIG);
  int b  = blockIdx.z;
  int p0 = blockIdx.x * 64;

  int t = threadIdx.x, l = t & 63, w = t >> 6;
  int q = l >> 4, n = l & 15;

  f32x4 acc[4][4];
#pragma unroll
  for (int i = 0; i < 4; i++)
#pragma unroll
    for (int j = 0; j < 4; j++)
#pragma unroll
      for (int r = 0; r < 4; r++) acc[i][j][r] = 0.f;

  const f16* bbase = yh2 + (size_t)(b * 48 + q) * (HW * 8) + (size_t)(p0 + n) * 8;
  const f16* abase = wt2g + (size_t)(w * 4) * 512 + (size_t)l * 8;

#pragma unroll 2
  for (int ks = 0; ks < 12; ks++) {
    f16x8 afr[4], bfr[4];
#pragma unroll
    for (int mt = 0; mt < 4; mt++)
      afr[mt] = *(const f16x8*)(abase + (size_t)(ks * 16 + mt) * 512);
#pragma unroll
    for (int nt = 0; nt < 4; nt++)
      bfr[nt] = *(const f16x8*)(bbase + (size_t)ks * (4 * HW * 8) + nt * 128);
#pragma unroll
    for (int mt = 0; mt < 4; mt++)
#pragma unroll
      for (int nt = 0; nt < 4; nt++)
        acc[mt][nt] = __builtin_amdgcn_mfma_f32_16x16x32_f16(afr[mt], bfr[nt],
                                                             acc[mt][nt], 0, 0, 0);
  }

#pragma unroll
  for (int mt = 0; mt < 4; mt++) {
    int obase = w * 64 + mt * 16 + q * 4;
    float bias[4];
#pragma unroll
    for (int r = 0; r < 4; r++) bias[r] = pw_b[obase + r];
#pragma unroll
    for (int nt = 0; nt < 4; nt++) {
      int p = p0 + nt * 16 + n;
#pragma unroll
      for (int r = 0; r < 4; r++) {
        size_t idx = ((size_t)b * O + obase + r) * HW + p;
        out[idx] = acc[mt][nt][r] + bias[r] + x[idx];
      }
    }
  }
}

// ---------------------------------------------------------------------------
extern "C" void kernel_launch(void* const* d_in, const int* in_sizes, int n_in,
                              void* d_out, int out_size, void* d_ws, size_t ws_size,
                              hipStream_t stream) {
  const float* x     = (const float*)d_in[0];
  const float* pw1_w = (const float*)d_in[1];
  const float* pw1_b = (const float*)d_in[2];
  const float* fc1_w = (const float*)d_in[3];
  const float* fc1_b = (const float*)d_in[4];
  const float* fc2_w = (const float*)d_in[5];
  const float* fc2_b = (const float*)d_in[6];
  const float* off_w = (const float*)d_in[7];
  const float* off_b = (const float*)d_in[8];
  const float* dw3   = (const float*)d_in[9];
  const float* dw5   = (const float*)d_in[10];
  const float* dw7   = (const float*)d_in[11];
  const float* pw_w  = (const float*)d_in[12];
  const float* pw_b  = (const float*)d_in[13];
  float* out = (float*)d_out;
  float* ws  = (float*)d_ws;

  kT<<<384, 256, 0, stream>>>(pw1_w, pw_w, ws);
  kAT<<<dim3(HW / 256, 32, B), 256, 0, stream>>>(x, ws);
  kB<<<B, 256, 0, stream>>>(pw1_w, pw1_b, fc1_w, fc1_b, fc2_w, fc2_b, ws);
  kCm<<<dim3(HW / 64, 1, B), 256, 0, stream>>>(pw1_b, ws);
  kD1<<<1, 256, 0, stream>>>(off_w, off_b, ws);
  kD2<<<84, 256, 0, stream>>>(dw3, dw5, dw7, ws);
  kEm<<<dim3(16, 16, B), 256, 0, stream>>>(ws, ws);
  kFm<<<dim3(HW / 64, 1, B), 256, 0, stream>>>(x, pw_b, ws, out);
}